// Round 1
// baseline (5930.644 us; speedup 1.0000x reference)
//
#include <hip/hip_runtime.h>
#include <cstdint>
#include <cstddef>

#define DD 128

// ---------------- CSR build ----------------

__global__ void count_deg_k(const int* __restrict__ dst, int* __restrict__ deg, int E) {
    int i = blockIdx.x * blockDim.x + threadIdx.x;
    if (i < E) atomicAdd(&deg[dst[i]], 1);
}

__global__ __launch_bounds__(1024) void scan_k(const int* __restrict__ deg,
                                               int* __restrict__ rp,
                                               int* __restrict__ cur, int n) {
    __shared__ int sums[1024];
    int tid = threadIdx.x;
    int per = (n + 1023) >> 10;
    int start = tid * per;
    int end = min(start + per, n);
    int s = 0;
    for (int i = start; i < end; ++i) s += deg[i];
    sums[tid] = s;
    __syncthreads();
    for (int off = 1; off < 1024; off <<= 1) {
        int v = (tid >= off) ? sums[tid - off] : 0;
        __syncthreads();
        sums[tid] += v;
        __syncthreads();
    }
    int pre = (tid == 0) ? 0 : sums[tid - 1];
    for (int i = start; i < end; ++i) {
        rp[i] = pre;
        cur[i] = pre;
        pre += deg[i];
    }
    if (end == n) rp[n] = pre;   // pre == total for all threads at/after the boundary
}

__global__ void fill_k(const int* __restrict__ src, const int* __restrict__ dst,
                       const float* __restrict__ w, int* __restrict__ cur,
                       int2* __restrict__ edges, int E) {
    int i = blockIdx.x * blockDim.x + threadIdx.x;
    if (i < E) {
        int d = dst[i];
        int pos = atomicAdd(&cur[d], 1);
        edges[pos] = make_int2(src[i], __float_as_int(w[i]));
    }
}

// ---------------- P = H H^T, S = H + H^T (both symmetric) ----------------

__global__ __launch_bounds__(256) void prep_k(const float* __restrict__ H,
                                              float* __restrict__ P,
                                              float* __restrict__ S) {
    int idx = blockIdx.x * 256 + threadIdx.x;   // 0..16383
    int i = idx >> 7, j = idx & 127;
    float acc = 0.f;
    for (int k = 0; k < DD; ++k) acc += H[i * DD + k] * H[j * DD + k];
    P[idx] = acc;
    S[idx] = H[i * DD + j] + H[j * DD + i];
}

// ---------------- SpMM: out[i] = sum_{e: dst=i} w_e * Y[src_e]  (CSR gather) ----------------

__global__ __launch_bounds__(256) void spmm_k(const int* __restrict__ rp,
                                              const int2* __restrict__ edges,
                                              const float* __restrict__ Y,
                                              float* __restrict__ out, int n) {
    int node = blockIdx.x * 4 + (threadIdx.x >> 6);
    if (node >= n) return;
    int lane = threadIdx.x & 63;
    int beg = rp[node], end = rp[node + 1];
    float a0 = 0.f, a1 = 0.f;
    for (int j = beg; j < end; ++j) {
        int2 e = edges[j];
        float wv = __int_as_float(e.y);
        const float* yr = Y + (size_t)e.x * DD;
        a0 += wv * yr[lane];
        a1 += wv * yr[lane + 64];
    }
    out[(size_t)node * DD + lane] = a0;
    out[(size_t)node * DD + lane + 64] = a1;
}

// ---------------- Fused dense step ----------------
// accP1 = Y@P1, accP2 = Y@P2, accS = Ab@S1 + Ag@S2, then
// Yhat = accS - db*accP1 - dg*accP2 + X + dg*Y - Ag
// Yn   = (2/3) Y + (1/3) * Yhat / (db+dg+1)

__global__ __launch_bounds__(256) void dense_k(
    const float* __restrict__ Y, const float* __restrict__ X,
    const float* __restrict__ Ab, const float* __restrict__ Ag,
    const float* __restrict__ db, const float* __restrict__ dg,
    const float* __restrict__ P1, const float* __restrict__ P2,
    const float* __restrict__ S1, const float* __restrict__ S2,
    float* __restrict__ Yn, int n)
{
    __shared__ float Asm[64][132];
    __shared__ float B1[16][128];
    __shared__ float B2[16][128];

    const int tid = threadIdx.x;
    const int cg = tid & 15;    // col group: cols cg*8 .. cg*8+7
    const int rg = tid >> 4;    // row group: rows rg*4 .. rg*4+3
    const int row0 = blockIdx.x * 64;

    float accP1[4][8], accP2[4][8], accS[4][8];
#pragma unroll
    for (int i = 0; i < 4; ++i)
#pragma unroll
        for (int j = 0; j < 8; ++j) { accP1[i][j] = 0.f; accP2[i][j] = 0.f; accS[i][j] = 0.f; }

    auto stageA = [&](const float* __restrict__ G) {
        int r = tid >> 2;
        int rowc = min(row0 + r, n - 1);
        const float* gp = G + (size_t)rowc * DD;
#pragma unroll
        for (int i = 0; i < 8; ++i) {
            int c = ((tid & 3) << 2) + (i << 4);
            float4 v = *reinterpret_cast<const float4*>(gp + c);
            *reinterpret_cast<float4*>(&Asm[r][c]) = v;
        }
    };
    auto stageB = [&](const float* __restrict__ M, int kk, float (*Bs)[128]) {
        int kloc = tid >> 4;   // 0..15
        int cseg = tid & 15;   // 0..15
        const float* gp = M + (size_t)(kk * 16 + kloc) * DD + cseg * 8;
        float4 v0 = *reinterpret_cast<const float4*>(gp);
        float4 v1 = *reinterpret_cast<const float4*>(gp + 4);
        // split layout: low halves in [0..63], high halves in [64..127] -> conflict-free b128 reads
        *reinterpret_cast<float4*>(&Bs[kloc][cseg * 4]) = v0;
        *reinterpret_cast<float4*>(&Bs[kloc][64 + cseg * 4]) = v1;
    };

    // ---- Phase 1: A = Y, accumulate Y@P1, Y@P2 ----
    stageA(Y);
    __syncthreads();
    for (int kk = 0; kk < 8; ++kk) {
        stageB(P1, kk, B1);
        stageB(P2, kk, B2);
        __syncthreads();
#pragma unroll
        for (int k2 = 0; k2 < 16; ++k2) {
            int k = kk * 16 + k2;
            float a[4];
#pragma unroll
            for (int i = 0; i < 4; ++i) a[i] = Asm[rg * 4 + i][k];
            float4 b1l = *reinterpret_cast<const float4*>(&B1[k2][cg * 4]);
            float4 b1h = *reinterpret_cast<const float4*>(&B1[k2][64 + cg * 4]);
            float4 b2l = *reinterpret_cast<const float4*>(&B2[k2][cg * 4]);
            float4 b2h = *reinterpret_cast<const float4*>(&B2[k2][64 + cg * 4]);
            float b1v[8] = {b1l.x, b1l.y, b1l.z, b1l.w, b1h.x, b1h.y, b1h.z, b1h.w};
            float b2v[8] = {b2l.x, b2l.y, b2l.z, b2l.w, b2h.x, b2h.y, b2h.z, b2h.w};
#pragma unroll
            for (int i = 0; i < 4; ++i)
#pragma unroll
                for (int j = 0; j < 8; ++j) {
                    accP1[i][j] += a[i] * b1v[j];
                    accP2[i][j] += a[i] * b2v[j];
                }
        }
        __syncthreads();
    }

    // ---- Phase 2: A = Ab, accS += Ab@S1 ----
    stageA(Ab);
    __syncthreads();
    for (int kk = 0; kk < 8; ++kk) {
        stageB(S1, kk, B1);
        __syncthreads();
#pragma unroll
        for (int k2 = 0; k2 < 16; ++k2) {
            int k = kk * 16 + k2;
            float a[4];
#pragma unroll
            for (int i = 0; i < 4; ++i) a[i] = Asm[rg * 4 + i][k];
            float4 bl = *reinterpret_cast<const float4*>(&B1[k2][cg * 4]);
            float4 bh = *reinterpret_cast<const float4*>(&B1[k2][64 + cg * 4]);
            float bv[8] = {bl.x, bl.y, bl.z, bl.w, bh.x, bh.y, bh.z, bh.w};
#pragma unroll
            for (int i = 0; i < 4; ++i)
#pragma unroll
                for (int j = 0; j < 8; ++j) accS[i][j] += a[i] * bv[j];
        }
        __syncthreads();
    }

    // ---- Phase 3: A = Ag, accS += Ag@S2 (Asm keeps Ag for the epilogue) ----
    stageA(Ag);
    __syncthreads();
    for (int kk = 0; kk < 8; ++kk) {
        stageB(S2, kk, B1);
        __syncthreads();
#pragma unroll
        for (int k2 = 0; k2 < 16; ++k2) {
            int k = kk * 16 + k2;
            float a[4];
#pragma unroll
            for (int i = 0; i < 4; ++i) a[i] = Asm[rg * 4 + i][k];
            float4 bl = *reinterpret_cast<const float4*>(&B1[k2][cg * 4]);
            float4 bh = *reinterpret_cast<const float4*>(&B1[k2][64 + cg * 4]);
            float bv[8] = {bl.x, bl.y, bl.z, bl.w, bh.x, bh.y, bh.z, bh.w};
#pragma unroll
            for (int i = 0; i < 4; ++i)
#pragma unroll
                for (int j = 0; j < 8; ++j) accS[i][j] += a[i] * bv[j];
        }
        __syncthreads();
    }

    // ---- Epilogue ----
    const float AL = 1.0f / 3.0f;
#pragma unroll
    for (int i = 0; i < 4; ++i) {
        int r = rg * 4 + i;
        int row = row0 + r;
        if (row < n) {
            float dbv = db[row], dgv = dg[row];
            float aq = AL / (dbv + dgv + 1.0f);
            const float* yp = Y + (size_t)row * DD + cg * 8;
            const float* xp = X + (size_t)row * DD + cg * 8;
            float4 y0 = *reinterpret_cast<const float4*>(yp);
            float4 y1 = *reinterpret_cast<const float4*>(yp + 4);
            float4 x0 = *reinterpret_cast<const float4*>(xp);
            float4 x1 = *reinterpret_cast<const float4*>(xp + 4);
            float yv[8] = {y0.x, y0.y, y0.z, y0.w, y1.x, y1.y, y1.z, y1.w};
            float xv[8] = {x0.x, x0.y, x0.z, x0.w, x1.x, x1.y, x1.z, x1.w};
            float ov[8];
#pragma unroll
            for (int j = 0; j < 8; ++j) {
                float agv = Asm[r][cg * 8 + j];
                float yhat = accS[i][j] - dbv * accP1[i][j] - dgv * accP2[i][j]
                             + xv[j] + dgv * yv[j] - agv;
                ov[j] = (1.0f - AL) * yv[j] + yhat * aq;
            }
            float* op = Yn + (size_t)row * DD + cg * 8;
            *reinterpret_cast<float4*>(op) = make_float4(ov[0], ov[1], ov[2], ov[3]);
            *reinterpret_cast<float4*>(op + 4) = make_float4(ov[4], ov[5], ov[6], ov[7]);
        }
    }
}

// ---------------- host ----------------

extern "C" void kernel_launch(void* const* d_in, const int* in_sizes, int n_in,
                              void* d_out, int out_size, void* d_ws, size_t ws_size,
                              hipStream_t stream) {
    const float* X   = (const float*)d_in[0];
    const float* H1  = (const float*)d_in[1];
    const float* H2  = (const float*)d_in[2];
    const float* wb  = (const float*)d_in[3];
    const float* wg  = (const float*)d_in[4];
    const float* db  = (const float*)d_in[5];
    const float* dg  = (const float*)d_in[6];
    const int* srcb  = (const int*)d_in[7];
    const int* dstb  = (const int*)d_in[8];
    const int* srcg  = (const int*)d_in[9];
    const int* dstg  = (const int*)d_in[10];
    const int N = in_sizes[5];
    const int E = in_sizes[3];
    float* Yout = (float*)d_out;

    char* p = (char*)d_ws;
    auto alloc = [&](size_t b) -> void* {
        void* r = (void*)p;
        p += (b + 255) & ~(size_t)255;
        return r;
    };
    float* P1 = (float*)alloc((size_t)DD * DD * 4);
    float* S1 = (float*)alloc((size_t)DD * DD * 4);
    float* P2 = (float*)alloc((size_t)DD * DD * 4);
    float* S2 = (float*)alloc((size_t)DD * DD * 4);
    int* degb = (int*)alloc((size_t)N * 4);
    int* degg = (int*)alloc((size_t)N * 4);
    int* rpb  = (int*)alloc((size_t)(N + 1) * 4);
    int* rpg  = (int*)alloc((size_t)(N + 1) * 4);
    int* curb = (int*)alloc((size_t)N * 4);
    int* curg = (int*)alloc((size_t)N * 4);
    int2* eb  = (int2*)alloc((size_t)E * 8);
    int2* eg  = (int2*)alloc((size_t)E * 8);
    float* AbY = (float*)alloc((size_t)N * DD * 4);
    float* AgY = (float*)alloc((size_t)N * DD * 4);
    float* Yw  = (float*)alloc((size_t)N * DD * 4);

    hipMemsetAsync(degb, 0, (size_t)N * 4, stream);
    hipMemsetAsync(degg, 0, (size_t)N * 4, stream);

    int gE = (E + 255) / 256;
    count_deg_k<<<gE, 256, 0, stream>>>(dstb, degb, E);
    count_deg_k<<<gE, 256, 0, stream>>>(dstg, degg, E);
    scan_k<<<1, 1024, 0, stream>>>(degb, rpb, curb, N);
    scan_k<<<1, 1024, 0, stream>>>(degg, rpg, curg, N);
    fill_k<<<gE, 256, 0, stream>>>(srcb, dstb, wb, curb, eb, E);
    fill_k<<<gE, 256, 0, stream>>>(srcg, dstg, wg, curg, eg, E);
    prep_k<<<64, 256, 0, stream>>>(H1, P1, S1);
    prep_k<<<64, 256, 0, stream>>>(H2, P2, S2);

    const float* Ycur = X;
    float* Ybufs[2] = {Yw, Yout};
    int gs = (N + 3) / 4;
    int gd = (N + 63) / 64;
    for (int s = 0; s < 8; ++s) {
        spmm_k<<<gs, 256, 0, stream>>>(rpb, eb, Ycur, AbY, N);
        spmm_k<<<gs, 256, 0, stream>>>(rpg, eg, Ycur, AgY, N);
        float* Yn = Ybufs[s & 1];
        dense_k<<<gd, 256, 0, stream>>>(Ycur, X, AbY, AgY, db, dg,
                                        P1, P2, S1, S2, Yn, N);
        Ycur = Yn;
    }
}

// Round 2
// 5338.922 us; speedup vs baseline: 1.1108x; 1.1108x over previous
//
#include <hip/hip_runtime.h>
#include <cstdint>
#include <cstddef>

#define DD 128

// ---------------- CSR build ----------------

__global__ void count_deg_k(const int* __restrict__ dst, int* __restrict__ deg, int E) {
    int i = blockIdx.x * blockDim.x + threadIdx.x;
    if (i < E) atomicAdd(&deg[dst[i]], 1);
}

__global__ __launch_bounds__(1024) void scan_k(const int* __restrict__ deg,
                                               int* __restrict__ rp,
                                               int* __restrict__ cur, int n) {
    __shared__ int sums[1024];
    int tid = threadIdx.x;
    int per = (n + 1023) >> 10;
    int start = tid * per;
    int end = min(start + per, n);
    int s = 0;
    for (int i = start; i < end; ++i) s += deg[i];
    sums[tid] = s;
    __syncthreads();
    for (int off = 1; off < 1024; off <<= 1) {
        int v = (tid >= off) ? sums[tid - off] : 0;
        __syncthreads();
        sums[tid] += v;
        __syncthreads();
    }
    int pre = (tid == 0) ? 0 : sums[tid - 1];
    for (int i = start; i < end; ++i) {
        rp[i] = pre;
        cur[i] = pre;
        pre += deg[i];
    }
    if (end == n) rp[n] = pre;
}

__global__ void fill_k(const int* __restrict__ src, const int* __restrict__ dst,
                       const float* __restrict__ w, int* __restrict__ cur,
                       int2* __restrict__ edges, int E) {
    int i = blockIdx.x * blockDim.x + threadIdx.x;
    if (i < E) {
        int d = dst[i];
        int pos = atomicAdd(&cur[d], 1);
        edges[pos] = make_int2(src[i], __float_as_int(w[i]));
    }
}

// ---------------- P = H H^T, S = H + H^T ----------------

__global__ __launch_bounds__(256) void prep_k(const float* __restrict__ H,
                                              float* __restrict__ P,
                                              float* __restrict__ S) {
    int idx = blockIdx.x * 256 + threadIdx.x;
    int i = idx >> 7, j = idx & 127;
    float acc = 0.f;
    for (int k = 0; k < DD; ++k) acc += H[i * DD + k] * H[j * DD + k];
    P[idx] = acc;
    S[idx] = H[i * DD + j] + H[j * DD + i];
}

// ---------------- SpMM: CSR gather, 1 wave per node, float2 lanes, 4x unroll ----------------

__global__ __launch_bounds__(256) void spmm_k(const int* __restrict__ rp,
                                              const int2* __restrict__ edges,
                                              const float* __restrict__ Y,
                                              float* __restrict__ out, int n) {
    int node = blockIdx.x * 4 + (threadIdx.x >> 6);
    if (node >= n) return;
    int lane = threadIdx.x & 63;
    int beg = rp[node], end = rp[node + 1];
    float a0 = 0.f, a1 = 0.f;
    int j = beg;
    for (; j + 4 <= end; j += 4) {
        int2 e0 = edges[j + 0];
        int2 e1 = edges[j + 1];
        int2 e2 = edges[j + 2];
        int2 e3 = edges[j + 3];
        float2 f0 = *((const float2*)(Y + (size_t)e0.x * DD) + lane);
        float2 f1 = *((const float2*)(Y + (size_t)e1.x * DD) + lane);
        float2 f2 = *((const float2*)(Y + (size_t)e2.x * DD) + lane);
        float2 f3 = *((const float2*)(Y + (size_t)e3.x * DD) + lane);
        float w0 = __int_as_float(e0.y), w1 = __int_as_float(e1.y);
        float w2 = __int_as_float(e2.y), w3 = __int_as_float(e3.y);
        a0 += w0 * f0.x; a1 += w0 * f0.y;
        a0 += w1 * f1.x; a1 += w1 * f1.y;
        a0 += w2 * f2.x; a1 += w2 * f2.y;
        a0 += w3 * f3.x; a1 += w3 * f3.y;
    }
    for (; j < end; ++j) {
        int2 e = edges[j];
        float2 f = *((const float2*)(Y + (size_t)e.x * DD) + lane);
        float wv = __int_as_float(e.y);
        a0 += wv * f.x; a1 += wv * f.y;
    }
    *((float2*)(out + (size_t)node * DD) + lane) = make_float2(a0, a1);
}

// ---------------- Fused dense step ----------------
// accP1 = Y@P1, accP2 = Y@P2, accS = Ab@S1 + Ag@S2
// Yhat = accS - db*accP1 - dg*accP2 + X + dg*Y - Ag
// Yn   = (2/3) Y + (1/3) * Yhat / (db+dg+1)
// A^T staged in LDS [128][68] (2-way conflicts only); B read straight from
// global (L1/L2 broadcast) with unrolled k loop -> 5 barriers total.

__global__ __launch_bounds__(256, 3) void dense_k(
    const float* __restrict__ Y, const float* __restrict__ X,
    const float* __restrict__ Ab, const float* __restrict__ Ag,
    const float* __restrict__ db, const float* __restrict__ dg,
    const float* __restrict__ P1, const float* __restrict__ P2,
    const float* __restrict__ S1, const float* __restrict__ S2,
    float* __restrict__ Yn, int n)
{
    __shared__ float At[DD][68];

    const int tid = threadIdx.x;
    const int cg = tid & 15;    // col group: cols cg*8 .. cg*8+7
    const int rg = tid >> 4;    // row group: rows rg*4 .. rg*4+3
    const int row0 = blockIdx.x * 64;

    float accP1[4][8], accP2[4][8], accS[4][8];
#pragma unroll
    for (int i = 0; i < 4; ++i)
#pragma unroll
        for (int j = 0; j < 8; ++j) { accP1[i][j] = 0.f; accP2[i][j] = 0.f; accS[i][j] = 0.f; }

    auto stageAT = [&](const float* __restrict__ G) {
        int r = tid >> 2;                       // 0..63
        int rowc = min(row0 + r, n - 1);
        const float* gp = G + (size_t)rowc * DD;
#pragma unroll
        for (int i = 0; i < 8; ++i) {
            int c = ((tid & 3) << 2) + (i << 4);
            float4 v = *reinterpret_cast<const float4*>(gp + c);
            At[c + 0][r] = v.x;
            At[c + 1][r] = v.y;
            At[c + 2][r] = v.z;
            At[c + 3][r] = v.w;
        }
    };

    const float* b1base = P1 + cg * 8;
    const float* b2base = P2 + cg * 8;

    // ---- Phase 1: A = Y -> accP1, accP2 ----
    stageAT(Y);
    __syncthreads();
#pragma unroll 2
    for (int k = 0; k < DD; ++k) {
        float4 a = *reinterpret_cast<const float4*>(&At[k][rg * 4]);
        float4 p10 = *reinterpret_cast<const float4*>(b1base + k * DD);
        float4 p11 = *reinterpret_cast<const float4*>(b1base + k * DD + 4);
        float4 p20 = *reinterpret_cast<const float4*>(b2base + k * DD);
        float4 p21 = *reinterpret_cast<const float4*>(b2base + k * DD + 4);
        float av[4] = {a.x, a.y, a.z, a.w};
        float b1v[8] = {p10.x, p10.y, p10.z, p10.w, p11.x, p11.y, p11.z, p11.w};
        float b2v[8] = {p20.x, p20.y, p20.z, p20.w, p21.x, p21.y, p21.z, p21.w};
#pragma unroll
        for (int i = 0; i < 4; ++i)
#pragma unroll
            for (int j = 0; j < 8; ++j) {
                accP1[i][j] += av[i] * b1v[j];
                accP2[i][j] += av[i] * b2v[j];
            }
    }

    // ---- Phase 2: A = Ab -> accS += Ab@S1 ----
    __syncthreads();
    stageAT(Ab);
    __syncthreads();
    {
        const float* bb = S1 + cg * 8;
#pragma unroll 4
        for (int k = 0; k < DD; ++k) {
            float4 a = *reinterpret_cast<const float4*>(&At[k][rg * 4]);
            float4 b0 = *reinterpret_cast<const float4*>(bb + k * DD);
            float4 b1 = *reinterpret_cast<const float4*>(bb + k * DD + 4);
            float av[4] = {a.x, a.y, a.z, a.w};
            float bv[8] = {b0.x, b0.y, b0.z, b0.w, b1.x, b1.y, b1.z, b1.w};
#pragma unroll
            for (int i = 0; i < 4; ++i)
#pragma unroll
                for (int j = 0; j < 8; ++j) accS[i][j] += av[i] * bv[j];
        }
    }

    // ---- Phase 3: A = Ag -> accS += Ag@S2 ----
    __syncthreads();
    stageAT(Ag);
    __syncthreads();
    {
        const float* bb = S2 + cg * 8;
#pragma unroll 4
        for (int k = 0; k < DD; ++k) {
            float4 a = *reinterpret_cast<const float4*>(&At[k][rg * 4]);
            float4 b0 = *reinterpret_cast<const float4*>(bb + k * DD);
            float4 b1 = *reinterpret_cast<const float4*>(bb + k * DD + 4);
            float av[4] = {a.x, a.y, a.z, a.w};
            float bv[8] = {b0.x, b0.y, b0.z, b0.w, b1.x, b1.y, b1.z, b1.w};
#pragma unroll
            for (int i = 0; i < 4; ++i)
#pragma unroll
                for (int j = 0; j < 8; ++j) accS[i][j] += av[i] * bv[j];
        }
    }

    // ---- Epilogue ----
    const float AL = 1.0f / 3.0f;
#pragma unroll
    for (int i = 0; i < 4; ++i) {
        int r = rg * 4 + i;
        int row = row0 + r;
        if (row < n) {
            float dbv = db[row], dgv = dg[row];
            float aq = AL / (dbv + dgv + 1.0f);
            const float* yp = Y + (size_t)row * DD + cg * 8;
            const float* xp = X + (size_t)row * DD + cg * 8;
            const float* ap = Ag + (size_t)row * DD + cg * 8;
            float4 y0 = *reinterpret_cast<const float4*>(yp);
            float4 y1 = *reinterpret_cast<const float4*>(yp + 4);
            float4 x0 = *reinterpret_cast<const float4*>(xp);
            float4 x1 = *reinterpret_cast<const float4*>(xp + 4);
            float4 g0 = *reinterpret_cast<const float4*>(ap);
            float4 g1 = *reinterpret_cast<const float4*>(ap + 4);
            float yv[8] = {y0.x, y0.y, y0.z, y0.w, y1.x, y1.y, y1.z, y1.w};
            float xv[8] = {x0.x, x0.y, x0.z, x0.w, x1.x, x1.y, x1.z, x1.w};
            float gv[8] = {g0.x, g0.y, g0.z, g0.w, g1.x, g1.y, g1.z, g1.w};
            float ov[8];
#pragma unroll
            for (int j = 0; j < 8; ++j) {
                float yhat = accS[i][j] - dbv * accP1[i][j] - dgv * accP2[i][j]
                             + xv[j] + dgv * yv[j] - gv[j];
                ov[j] = (1.0f - AL) * yv[j] + yhat * aq;
            }
            float* op = Yn + (size_t)row * DD + cg * 8;
            *reinterpret_cast<float4*>(op) = make_float4(ov[0], ov[1], ov[2], ov[3]);
            *reinterpret_cast<float4*>(op + 4) = make_float4(ov[4], ov[5], ov[6], ov[7]);
        }
    }
}

// ---------------- host ----------------

extern "C" void kernel_launch(void* const* d_in, const int* in_sizes, int n_in,
                              void* d_out, int out_size, void* d_ws, size_t ws_size,
                              hipStream_t stream) {
    const float* X   = (const float*)d_in[0];
    const float* H1  = (const float*)d_in[1];
    const float* H2  = (const float*)d_in[2];
    const float* wb  = (const float*)d_in[3];
    const float* wg  = (const float*)d_in[4];
    const float* db  = (const float*)d_in[5];
    const float* dg  = (const float*)d_in[6];
    const int* srcb  = (const int*)d_in[7];
    const int* dstb  = (const int*)d_in[8];
    const int* srcg  = (const int*)d_in[9];
    const int* dstg  = (const int*)d_in[10];
    const int N = in_sizes[5];
    const int E = in_sizes[3];
    float* Yout = (float*)d_out;

    char* p = (char*)d_ws;
    auto alloc = [&](size_t b) -> void* {
        void* r = (void*)p;
        p += (b + 255) & ~(size_t)255;
        return r;
    };
    float* P1 = (float*)alloc((size_t)DD * DD * 4);
    float* S1 = (float*)alloc((size_t)DD * DD * 4);
    float* P2 = (float*)alloc((size_t)DD * DD * 4);
    float* S2 = (float*)alloc((size_t)DD * DD * 4);
    int* degb = (int*)alloc((size_t)N * 4);
    int* degg = (int*)alloc((size_t)N * 4);
    int* rpb  = (int*)alloc((size_t)(N + 1) * 4);
    int* rpg  = (int*)alloc((size_t)(N + 1) * 4);
    int* curb = (int*)alloc((size_t)N * 4);
    int* curg = (int*)alloc((size_t)N * 4);
    int2* eb  = (int2*)alloc((size_t)E * 8);
    int2* eg  = (int2*)alloc((size_t)E * 8);
    float* AbY = (float*)alloc((size_t)N * DD * 4);
    float* AgY = (float*)alloc((size_t)N * DD * 4);
    float* Yw  = (float*)alloc((size_t)N * DD * 4);

    hipMemsetAsync(degb, 0, (size_t)N * 4, stream);
    hipMemsetAsync(degg, 0, (size_t)N * 4, stream);

    int gE = (E + 255) / 256;
    count_deg_k<<<gE, 256, 0, stream>>>(dstb, degb, E);
    count_deg_k<<<gE, 256, 0, stream>>>(dstg, degg, E);
    scan_k<<<1, 1024, 0, stream>>>(degb, rpb, curb, N);
    scan_k<<<1, 1024, 0, stream>>>(degg, rpg, curg, N);
    fill_k<<<gE, 256, 0, stream>>>(srcb, dstb, wb, curb, eb, E);
    fill_k<<<gE, 256, 0, stream>>>(srcg, dstg, wg, curg, eg, E);
    prep_k<<<64, 256, 0, stream>>>(H1, P1, S1);
    prep_k<<<64, 256, 0, stream>>>(H2, P2, S2);

    const float* Ycur = X;
    float* Ybufs[2] = {Yw, Yout};
    int gs = (N + 3) / 4;
    int gd = (N + 63) / 64;
    for (int s = 0; s < 8; ++s) {
        spmm_k<<<gs, 256, 0, stream>>>(rpb, eb, Ycur, AbY, N);
        spmm_k<<<gs, 256, 0, stream>>>(rpg, eg, Ycur, AgY, N);
        float* Yn = Ybufs[s & 1];
        dense_k<<<gd, 256, 0, stream>>>(Ycur, X, AbY, AgY, db, dg,
                                        P1, P2, S1, S2, Yn, N);
        Ycur = Yn;
    }
}

// Round 3
// 4352.605 us; speedup vs baseline: 1.3626x; 1.2266x over previous
//
#include <hip/hip_runtime.h>
#include <cstdint>
#include <cstddef>

#define DD 128

// ---------------- CSR build ----------------

__global__ void count_deg_k(const int* __restrict__ dst, int* __restrict__ deg, int E) {
    int i = blockIdx.x * blockDim.x + threadIdx.x;
    if (i < E) atomicAdd(&deg[dst[i]], 1);
}

__global__ __launch_bounds__(1024) void scan_k(const int* __restrict__ deg,
                                               int* __restrict__ rp,
                                               int* __restrict__ cur, int n) {
    __shared__ int sums[1024];
    int tid = threadIdx.x;
    int per = (n + 1023) >> 10;
    int start = tid * per;
    int end = min(start + per, n);
    int s = 0;
    for (int i = start; i < end; ++i) s += deg[i];
    sums[tid] = s;
    __syncthreads();
    for (int off = 1; off < 1024; off <<= 1) {
        int v = (tid >= off) ? sums[tid - off] : 0;
        __syncthreads();
        sums[tid] += v;
        __syncthreads();
    }
    int pre = (tid == 0) ? 0 : sums[tid - 1];
    for (int i = start; i < end; ++i) {
        rp[i] = pre;
        cur[i] = pre;
        pre += deg[i];
    }
    if (end == n) rp[n] = pre;
}

__global__ void fill_k(const int* __restrict__ src, const int* __restrict__ dst,
                       const float* __restrict__ w, int* __restrict__ cur,
                       int2* __restrict__ edges, int E) {
    int i = blockIdx.x * blockDim.x + threadIdx.x;
    if (i < E) {
        int d = dst[i];
        int pos = atomicAdd(&cur[d], 1);
        edges[pos] = make_int2(src[i], __float_as_int(w[i]));
    }
}

// ---------------- P = H H^T, S = H + H^T ----------------

__global__ __launch_bounds__(256) void prep_k(const float* __restrict__ H,
                                              float* __restrict__ P,
                                              float* __restrict__ S) {
    int idx = blockIdx.x * 256 + threadIdx.x;
    int i = idx >> 7, j = idx & 127;
    float acc = 0.f;
    for (int k = 0; k < DD; ++k) acc += H[i * DD + k] * H[j * DD + k];
    P[idx] = acc;
    S[idx] = H[i * DD + j] + H[j * DD + i];
}

// ---------------- SpMM: CSR gather, 2 nodes/wave (float4 lanes), 4x unroll ----------------

__global__ __launch_bounds__(256) void spmm_k(const int* __restrict__ rp,
                                              const int2* __restrict__ edges,
                                              const float* __restrict__ Y,
                                              float* __restrict__ out, int n) {
    int half_id = threadIdx.x >> 5;                 // 0..7 within block
    int node = blockIdx.x * 8 + half_id;
    if (node >= n) return;
    int lane = threadIdx.x & 31;                    // float4 lane within half-wave
    int beg = rp[node], end = rp[node + 1];
    float ax = 0.f, ay = 0.f, az = 0.f, aw = 0.f;
    int j = beg;
    for (; j + 4 <= end; j += 4) {
        int2 e0 = edges[j + 0];
        int2 e1 = edges[j + 1];
        int2 e2 = edges[j + 2];
        int2 e3 = edges[j + 3];
        float4 f0 = *((const float4*)(Y + (size_t)e0.x * DD) + lane);
        float4 f1 = *((const float4*)(Y + (size_t)e1.x * DD) + lane);
        float4 f2 = *((const float4*)(Y + (size_t)e2.x * DD) + lane);
        float4 f3 = *((const float4*)(Y + (size_t)e3.x * DD) + lane);
        float w0 = __int_as_float(e0.y), w1 = __int_as_float(e1.y);
        float w2 = __int_as_float(e2.y), w3 = __int_as_float(e3.y);
        ax += w0 * f0.x; ay += w0 * f0.y; az += w0 * f0.z; aw += w0 * f0.w;
        ax += w1 * f1.x; ay += w1 * f1.y; az += w1 * f1.z; aw += w1 * f1.w;
        ax += w2 * f2.x; ay += w2 * f2.y; az += w2 * f2.z; aw += w2 * f2.w;
        ax += w3 * f3.x; ay += w3 * f3.y; az += w3 * f3.z; aw += w3 * f3.w;
    }
    for (; j < end; ++j) {
        int2 e = edges[j];
        float4 f = *((const float4*)(Y + (size_t)e.x * DD) + lane);
        float wv = __int_as_float(e.y);
        ax += wv * f.x; ay += wv * f.y; az += wv * f.z; aw += wv * f.w;
    }
    *((float4*)(out + (size_t)node * DD) + lane) = make_float4(ax, ay, az, aw);
}

// ---------------- Fused dense step ----------------
// accP1 = Y@P1, accP2 = Y@P2, accS = Ab@S1 + Ag@S2
// Yhat = accS - db*accP1 - dg*accP2 + X + dg*Y - Ag
// Yn   = (2/3) Y + (1/3) * Yhat / (db+dg+1)
// A^T in LDS [128][68] f32; B staged per-matrix per-64-col-half in LDS (32KB).
// 2 blocks/CU, ~17 barriers, all inner-loop loads from LDS.

__global__ __launch_bounds__(256, 2) void dense_k(
    const float* __restrict__ Y, const float* __restrict__ X,
    const float* __restrict__ Ab, const float* __restrict__ Ag,
    const float* __restrict__ db, const float* __restrict__ dg,
    const float* __restrict__ P1, const float* __restrict__ P2,
    const float* __restrict__ S1, const float* __restrict__ S2,
    float* __restrict__ Yn, int n)
{
    __shared__ float At[DD][68];
    __shared__ float Bq[DD][64];

    const int tid = threadIdx.x;
    const int cg = tid & 15;    // col group within 64-col half: cols cg*4..cg*4+3
    const int rg = tid >> 4;    // row group: rows rg*4..rg*4+3
    const int row0 = blockIdx.x * 64;

    float accP1[2][4][4], accP2[2][4][4], accS[2][4][4];
#pragma unroll
    for (int h = 0; h < 2; ++h)
#pragma unroll
        for (int i = 0; i < 4; ++i)
#pragma unroll
            for (int j = 0; j < 4; ++j) {
                accP1[h][i][j] = 0.f; accP2[h][i][j] = 0.f; accS[h][i][j] = 0.f;
            }

    auto stageAt = [&](const float* __restrict__ G) {
        int r = tid >> 2;                       // 0..63
        int rowc = min(row0 + r, n - 1);
        const float* gp = G + (size_t)rowc * DD;
#pragma unroll
        for (int i = 0; i < 8; ++i) {
            int c = ((tid & 3) << 2) + (i << 4);
            float4 v = *reinterpret_cast<const float4*>(gp + c);
            At[c + 0][r] = v.x;
            At[c + 1][r] = v.y;
            At[c + 2][r] = v.z;
            At[c + 3][r] = v.w;
        }
    };
    auto stageB = [&](const float* __restrict__ M, int h) {
        int kb = tid >> 4;      // 0..15
        int c4 = tid & 15;      // 0..15 -> 4 cols
#pragma unroll
        for (int t = 0; t < 8; ++t) {
            int k = kb + t * 16;
            float4 v = *reinterpret_cast<const float4*>(M + (size_t)k * DD + h * 64 + c4 * 4);
            *reinterpret_cast<float4*>(&Bq[k][c4 * 4]) = v;
        }
    };
    auto kloop = [&](float (&acc)[4][4]) {
        const float* ap = &At[0][rg * 4];
        const float* bp = &Bq[0][cg * 4];
#pragma unroll 4
        for (int k = 0; k < DD; ++k) {
            float4 a = *reinterpret_cast<const float4*>(ap + k * 68);
            float4 b = *reinterpret_cast<const float4*>(bp + k * 64);
            float av[4] = {a.x, a.y, a.z, a.w};
            float bv[4] = {b.x, b.y, b.z, b.w};
#pragma unroll
            for (int i = 0; i < 4; ++i)
#pragma unroll
                for (int j = 0; j < 4; ++j) acc[i][j] += av[i] * bv[j];
        }
    };

    // Phase 1: A = Y -> accP1 (P1), accP2 (P2)
    stageAt(Y);
    __syncthreads();
#pragma unroll
    for (int h = 0; h < 2; ++h) {
        stageB(P1, h); __syncthreads();
        kloop(accP1[h]); __syncthreads();
    }
#pragma unroll
    for (int h = 0; h < 2; ++h) {
        stageB(P2, h); __syncthreads();
        kloop(accP2[h]); __syncthreads();
    }

    // Phase 2: A = Ab -> accS += Ab@S1
    stageAt(Ab);
    __syncthreads();
#pragma unroll
    for (int h = 0; h < 2; ++h) {
        stageB(S1, h); __syncthreads();
        kloop(accS[h]); __syncthreads();
    }

    // Phase 3: A = Ag -> accS += Ag@S2
    stageAt(Ag);
    __syncthreads();
#pragma unroll
    for (int h = 0; h < 2; ++h) {
        stageB(S2, h); __syncthreads();
        kloop(accS[h]); __syncthreads();
    }

    // Epilogue
    const float AL = 1.0f / 3.0f;
#pragma unroll
    for (int i = 0; i < 4; ++i) {
        int row = row0 + rg * 4 + i;
        if (row < n) {
            float dbv = db[row], dgv = dg[row];
            float aq = AL / (dbv + dgv + 1.0f);
#pragma unroll
            for (int h = 0; h < 2; ++h) {
                size_t off = (size_t)row * DD + h * 64 + cg * 4;
                float4 y = *reinterpret_cast<const float4*>(Y + off);
                float4 x = *reinterpret_cast<const float4*>(X + off);
                float4 g = *reinterpret_cast<const float4*>(Ag + off);
                float yv[4] = {y.x, y.y, y.z, y.w};
                float xv[4] = {x.x, x.y, x.z, x.w};
                float gv[4] = {g.x, g.y, g.z, g.w};
                float ov[4];
#pragma unroll
                for (int j = 0; j < 4; ++j) {
                    float yhat = accS[h][i][j] - dbv * accP1[h][i][j] - dgv * accP2[h][i][j]
                                 + xv[j] + dgv * yv[j] - gv[j];
                    ov[j] = (1.0f - AL) * yv[j] + yhat * aq;
                }
                *reinterpret_cast<float4*>(Yn + off) = make_float4(ov[0], ov[1], ov[2], ov[3]);
            }
        }
    }
}

// ---------------- host ----------------

extern "C" void kernel_launch(void* const* d_in, const int* in_sizes, int n_in,
                              void* d_out, int out_size, void* d_ws, size_t ws_size,
                              hipStream_t stream) {
    const float* X   = (const float*)d_in[0];
    const float* H1  = (const float*)d_in[1];
    const float* H2  = (const float*)d_in[2];
    const float* wb  = (const float*)d_in[3];
    const float* wg  = (const float*)d_in[4];
    const float* db  = (const float*)d_in[5];
    const float* dg  = (const float*)d_in[6];
    const int* srcb  = (const int*)d_in[7];
    const int* dstb  = (const int*)d_in[8];
    const int* srcg  = (const int*)d_in[9];
    const int* dstg  = (const int*)d_in[10];
    const int N = in_sizes[5];
    const int E = in_sizes[3];
    float* Yout = (float*)d_out;

    char* p = (char*)d_ws;
    auto alloc = [&](size_t b) -> void* {
        void* r = (void*)p;
        p += (b + 255) & ~(size_t)255;
        return r;
    };
    float* P1 = (float*)alloc((size_t)DD * DD * 4);
    float* S1 = (float*)alloc((size_t)DD * DD * 4);
    float* P2 = (float*)alloc((size_t)DD * DD * 4);
    float* S2 = (float*)alloc((size_t)DD * DD * 4);
    int* degb = (int*)alloc((size_t)N * 4);
    int* degg = (int*)alloc((size_t)N * 4);
    int* rpb  = (int*)alloc((size_t)(N + 1) * 4);
    int* rpg  = (int*)alloc((size_t)(N + 1) * 4);
    int* curb = (int*)alloc((size_t)N * 4);
    int* curg = (int*)alloc((size_t)N * 4);
    int2* eb  = (int2*)alloc((size_t)E * 8);
    int2* eg  = (int2*)alloc((size_t)E * 8);
    float* AbY = (float*)alloc((size_t)N * DD * 4);
    float* AgY = (float*)alloc((size_t)N * DD * 4);
    float* Yw  = (float*)alloc((size_t)N * DD * 4);

    hipMemsetAsync(degb, 0, (size_t)N * 4, stream);
    hipMemsetAsync(degg, 0, (size_t)N * 4, stream);

    int gE = (E + 255) / 256;
    count_deg_k<<<gE, 256, 0, stream>>>(dstb, degb, E);
    count_deg_k<<<gE, 256, 0, stream>>>(dstg, degg, E);
    scan_k<<<1, 1024, 0, stream>>>(degb, rpb, curb, N);
    scan_k<<<1, 1024, 0, stream>>>(degg, rpg, curg, N);
    fill_k<<<gE, 256, 0, stream>>>(srcb, dstb, wb, curb, eb, E);
    fill_k<<<gE, 256, 0, stream>>>(srcg, dstg, wg, curg, eg, E);
    prep_k<<<64, 256, 0, stream>>>(H1, P1, S1);
    prep_k<<<64, 256, 0, stream>>>(H2, P2, S2);

    const float* Ycur = X;
    float* Ybufs[2] = {Yw, Yout};
    int gs = (N + 7) / 8;
    int gd = (N + 63) / 64;
    for (int s = 0; s < 8; ++s) {
        spmm_k<<<gs, 256, 0, stream>>>(rpb, eb, Ycur, AbY, N);
        spmm_k<<<gs, 256, 0, stream>>>(rpg, eg, Ycur, AgY, N);
        float* Yn = Ybufs[s & 1];
        dense_k<<<gd, 256, 0, stream>>>(Ycur, X, AbY, AgY, db, dg,
                                        P1, P2, S1, S2, Yn, N);
        Ycur = Yn;
    }
}

// Round 4
// 4296.582 us; speedup vs baseline: 1.3803x; 1.0130x over previous
//
#include <hip/hip_runtime.h>
#include <cstdint>
#include <cstddef>

#define DD 128

// ---------------- CSR build (both graphs in one launch) ----------------

__global__ void count2_k(const int* __restrict__ dstb, const int* __restrict__ dstg,
                         int* __restrict__ degb, int* __restrict__ degg, int E, int gE) {
    int b = blockIdx.x;
    const int* dst = (b < gE) ? dstb : dstg;
    int* deg = (b < gE) ? degb : degg;
    int i = ((b < gE) ? b : b - gE) * blockDim.x + threadIdx.x;
    if (i < E) atomicAdd(&deg[dst[i]], 1);
}

__global__ __launch_bounds__(1024) void scan2_k(const int* __restrict__ degb,
                                                const int* __restrict__ degg,
                                                int* __restrict__ rpb, int* __restrict__ rpg,
                                                int* __restrict__ curb, int* __restrict__ curg,
                                                int n) {
    const int* deg = (blockIdx.x == 0) ? degb : degg;
    int* rp = (blockIdx.x == 0) ? rpb : rpg;
    int* cur = (blockIdx.x == 0) ? curb : curg;
    __shared__ int sums[1024];
    int tid = threadIdx.x;
    int per = (n + 1023) >> 10;
    int start = tid * per;
    int end = min(start + per, n);
    int s = 0;
    for (int i = start; i < end; ++i) s += deg[i];
    sums[tid] = s;
    __syncthreads();
    for (int off = 1; off < 1024; off <<= 1) {
        int v = (tid >= off) ? sums[tid - off] : 0;
        __syncthreads();
        sums[tid] += v;
        __syncthreads();
    }
    int pre = (tid == 0) ? 0 : sums[tid - 1];
    for (int i = start; i < end; ++i) {
        rp[i] = pre;
        cur[i] = pre;
        pre += deg[i];
    }
    if (end == n) rp[n] = pre;
}

__global__ void fill2_k(const int* __restrict__ srcb, const int* __restrict__ dstb,
                        const float* __restrict__ wb,
                        const int* __restrict__ srcg, const int* __restrict__ dstg,
                        const float* __restrict__ wg,
                        int* __restrict__ curb, int* __restrict__ curg,
                        int2* __restrict__ eb, int2* __restrict__ eg, int E, int gE) {
    int b = blockIdx.x;
    bool isb = (b < gE);
    const int* src = isb ? srcb : srcg;
    const int* dst = isb ? dstb : dstg;
    const float* w = isb ? wb : wg;
    int* cur = isb ? curb : curg;
    int2* edges = isb ? eb : eg;
    int i = (isb ? b : b - gE) * blockDim.x + threadIdx.x;
    if (i < E) {
        int d = dst[i];
        int pos = atomicAdd(&cur[d], 1);
        edges[pos] = make_int2(src[i], __float_as_int(w[i]));
    }
}

// ---------------- P = H H^T, S = H + H^T ----------------

__global__ __launch_bounds__(256) void prep_k(const float* __restrict__ H,
                                              float* __restrict__ P,
                                              float* __restrict__ S) {
    int idx = blockIdx.x * 256 + threadIdx.x;
    int i = idx >> 7, j = idx & 127;
    float acc = 0.f;
    for (int k = 0; k < DD; ++k) acc += H[i * DD + k] * H[j * DD + k];
    P[idx] = acc;
    S[idx] = H[i * DD + j] + H[j * DD + i];
}

// ---------------- SpMM: CSR gather, 1 wave per node, float2 lanes, 8x pipeline ----------------

__global__ __launch_bounds__(256) void spmm_k(const int* __restrict__ rp,
                                              const int2* __restrict__ edges,
                                              const float* __restrict__ Y,
                                              float* __restrict__ out, int n) {
    int node = blockIdx.x * 4 + (threadIdx.x >> 6);
    if (node >= n) return;
    int lane = threadIdx.x & 63;
    int beg = rp[node], end = rp[node + 1];
    float a0 = 0.f, a1 = 0.f;
    int j = beg;
    for (; j + 8 <= end; j += 8) {
        int2 e0 = edges[j + 0], e1 = edges[j + 1], e2 = edges[j + 2], e3 = edges[j + 3];
        int2 e4 = edges[j + 4], e5 = edges[j + 5], e6 = edges[j + 6], e7 = edges[j + 7];
        float2 f0 = *((const float2*)(Y + (size_t)e0.x * DD) + lane);
        float2 f1 = *((const float2*)(Y + (size_t)e1.x * DD) + lane);
        float2 f2 = *((const float2*)(Y + (size_t)e2.x * DD) + lane);
        float2 f3 = *((const float2*)(Y + (size_t)e3.x * DD) + lane);
        float2 f4 = *((const float2*)(Y + (size_t)e4.x * DD) + lane);
        float2 f5 = *((const float2*)(Y + (size_t)e5.x * DD) + lane);
        float2 f6 = *((const float2*)(Y + (size_t)e6.x * DD) + lane);
        float2 f7 = *((const float2*)(Y + (size_t)e7.x * DD) + lane);
        float w0 = __int_as_float(e0.y), w1 = __int_as_float(e1.y);
        float w2 = __int_as_float(e2.y), w3 = __int_as_float(e3.y);
        float w4 = __int_as_float(e4.y), w5 = __int_as_float(e5.y);
        float w6 = __int_as_float(e6.y), w7 = __int_as_float(e7.y);
        a0 += w0 * f0.x; a1 += w0 * f0.y;
        a0 += w1 * f1.x; a1 += w1 * f1.y;
        a0 += w2 * f2.x; a1 += w2 * f2.y;
        a0 += w3 * f3.x; a1 += w3 * f3.y;
        a0 += w4 * f4.x; a1 += w4 * f4.y;
        a0 += w5 * f5.x; a1 += w5 * f5.y;
        a0 += w6 * f6.x; a1 += w6 * f6.y;
        a0 += w7 * f7.x; a1 += w7 * f7.y;
    }
    for (; j + 4 <= end; j += 4) {
        int2 e0 = edges[j + 0], e1 = edges[j + 1], e2 = edges[j + 2], e3 = edges[j + 3];
        float2 f0 = *((const float2*)(Y + (size_t)e0.x * DD) + lane);
        float2 f1 = *((const float2*)(Y + (size_t)e1.x * DD) + lane);
        float2 f2 = *((const float2*)(Y + (size_t)e2.x * DD) + lane);
        float2 f3 = *((const float2*)(Y + (size_t)e3.x * DD) + lane);
        float w0 = __int_as_float(e0.y), w1 = __int_as_float(e1.y);
        float w2 = __int_as_float(e2.y), w3 = __int_as_float(e3.y);
        a0 += w0 * f0.x; a1 += w0 * f0.y;
        a0 += w1 * f1.x; a1 += w1 * f1.y;
        a0 += w2 * f2.x; a1 += w2 * f2.y;
        a0 += w3 * f3.x; a1 += w3 * f3.y;
    }
    for (; j < end; ++j) {
        int2 e = edges[j];
        float2 f = *((const float2*)(Y + (size_t)e.x * DD) + lane);
        float wv = __int_as_float(e.y);
        a0 += wv * f.x; a1 += wv * f.y;
    }
    *((float2*)(out + (size_t)node * DD) + lane) = make_float2(a0, a1);
}

// ---------------- Fused dense step ----------------
// Block: 64 rows x 128 cols, 128 threads, 8x8 thread tile (1.0 B/FMA LDS).
// Quarter-K staging: At[32][68] + B1[32][160] + B2[32][160] = ~50KB -> 3 blocks/CU.
// Phase 1 shares A=Y across P1,P2 (0.75 B/FMA).
// B layout: col-group g (8 cols) at words 10g.. (16B-aligned b64 reads, conflict-free).

#define ATS 68
#define BS 160

__global__ __launch_bounds__(128, 2) void dense_k(
    const float* __restrict__ Y, const float* __restrict__ X,
    const float* __restrict__ Ab, const float* __restrict__ Ag,
    const float* __restrict__ db, const float* __restrict__ dg,
    const float* __restrict__ P1, const float* __restrict__ P2,
    const float* __restrict__ S1, const float* __restrict__ S2,
    float* __restrict__ Yn, int n)
{
    __shared__ float At[32 * ATS];
    __shared__ float B1[32 * BS];
    __shared__ float B2[32 * BS];

    const int tid = threadIdx.x;
    const int cg = tid & 15;    // cols cg*8 .. cg*8+7
    const int rg = tid >> 4;    // 0..7 -> rows rg*8 .. rg*8+7
    const int row0 = blockIdx.x * 64;

    float aP1[8][8], aP2[8][8], aS[8][8];
#pragma unroll
    for (int i = 0; i < 8; ++i)
#pragma unroll
        for (int j = 0; j < 8; ++j) { aP1[i][j] = 0.f; aP2[i][j] = 0.f; aS[i][j] = 0.f; }

    // stage A quarter: At[kl][r] = A[row0+r][kq*32+kl]
    auto stageA = [&](const float* __restrict__ G, int kq) {
        int r = tid >> 1;                 // 0..63
        int kh = (tid & 1) * 16;
        int rowc = min(row0 + r, n - 1);
        const float* gp = G + (size_t)rowc * DD + kq * 32 + kh;
#pragma unroll
        for (int u = 0; u < 4; ++u) {
            float4 v = *reinterpret_cast<const float4*>(gp + 4 * u);
            int kb = kh + 4 * u;
            At[(kb + 0) * ATS + r] = v.x;
            At[(kb + 1) * ATS + r] = v.y;
            At[(kb + 2) * ATS + r] = v.z;
            At[(kb + 3) * ATS + r] = v.w;
        }
    };
    // stage B quarter: Bd[kl*BS + 10*(c>>3) + (c&7)] = M[kq*32+kl][c]
    auto stageB = [&](const float* __restrict__ M, float* __restrict__ Bd, int kq) {
        int kl = tid >> 2;                // 0..31
        int cb = (tid & 3) * 32;
        const float* gp = M + (size_t)(kq * 32 + kl) * DD + cb;
        float* bp = Bd + kl * BS;
#pragma unroll
        for (int u = 0; u < 8; ++u) {
            float4 v = *reinterpret_cast<const float4*>(gp + 4 * u);
            int c = cb + 4 * u;
            float vv[4] = {v.x, v.y, v.z, v.w};
#pragma unroll
            for (int q = 0; q < 4; ++q) {
                int cc = c + q;
                bp[10 * (cc >> 3) + (cc & 7)] = vv[q];
            }
        }
    };

    const int abase = rg * 8;
    const int bbase = 10 * cg;

    // ---- Phase 1: A=Y -> aP1 (P1), aP2 (P2), shared A-frag ----
    for (int kq = 0; kq < 4; ++kq) {
        if (kq) __syncthreads();
        stageA(Y, kq);
        stageB(P1, B1, kq);
        stageB(P2, B2, kq);
        __syncthreads();
#pragma unroll 2
        for (int kl = 0; kl < 32; ++kl) {
            float a[8], b1[8], b2[8];
            *reinterpret_cast<float4*>(&a[0]) = *reinterpret_cast<const float4*>(&At[kl * ATS + abase]);
            *reinterpret_cast<float4*>(&a[4]) = *reinterpret_cast<const float4*>(&At[kl * ATS + abase + 4]);
#pragma unroll
            for (int m = 0; m < 4; ++m) {
                *reinterpret_cast<float2*>(&b1[2 * m]) = *reinterpret_cast<const float2*>(&B1[kl * BS + bbase + 2 * m]);
                *reinterpret_cast<float2*>(&b2[2 * m]) = *reinterpret_cast<const float2*>(&B2[kl * BS + bbase + 2 * m]);
            }
#pragma unroll
            for (int i = 0; i < 8; ++i)
#pragma unroll
                for (int j = 0; j < 8; ++j) {
                    aP1[i][j] += a[i] * b1[j];
                    aP2[i][j] += a[i] * b2[j];
                }
        }
    }
    __syncthreads();

    // ---- Phase 2: A=Ab -> aS += Ab@S1 ----
    for (int kq = 0; kq < 4; ++kq) {
        if (kq) __syncthreads();
        stageA(Ab, kq);
        stageB(S1, B1, kq);
        __syncthreads();
#pragma unroll 2
        for (int kl = 0; kl < 32; ++kl) {
            float a[8], b1[8];
            *reinterpret_cast<float4*>(&a[0]) = *reinterpret_cast<const float4*>(&At[kl * ATS + abase]);
            *reinterpret_cast<float4*>(&a[4]) = *reinterpret_cast<const float4*>(&At[kl * ATS + abase + 4]);
#pragma unroll
            for (int m = 0; m < 4; ++m)
                *reinterpret_cast<float2*>(&b1[2 * m]) = *reinterpret_cast<const float2*>(&B1[kl * BS + bbase + 2 * m]);
#pragma unroll
            for (int i = 0; i < 8; ++i)
#pragma unroll
                for (int j = 0; j < 8; ++j) aS[i][j] += a[i] * b1[j];
        }
    }
    __syncthreads();

    // ---- Phase 3: A=Ag -> aS += Ag@S2 ----
    for (int kq = 0; kq < 4; ++kq) {
        if (kq) __syncthreads();
        stageA(Ag, kq);
        stageB(S2, B1, kq);
        __syncthreads();
#pragma unroll 2
        for (int kl = 0; kl < 32; ++kl) {
            float a[8], b1[8];
            *reinterpret_cast<float4*>(&a[0]) = *reinterpret_cast<const float4*>(&At[kl * ATS + abase]);
            *reinterpret_cast<float4*>(&a[4]) = *reinterpret_cast<const float4*>(&At[kl * ATS + abase + 4]);
#pragma unroll
            for (int m = 0; m < 4; ++m)
                *reinterpret_cast<float2*>(&b1[2 * m]) = *reinterpret_cast<const float2*>(&B1[kl * BS + bbase + 2 * m]);
#pragma unroll
            for (int i = 0; i < 8; ++i)
#pragma unroll
                for (int j = 0; j < 8; ++j) aS[i][j] += a[i] * b1[j];
        }
    }

    // ---- Epilogue ----
    const float AL = 1.0f / 3.0f;
#pragma unroll
    for (int i = 0; i < 8; ++i) {
        int row = row0 + rg * 8 + i;
        if (row < n) {
            float dbv = db[row], dgv = dg[row];
            float aq = AL / (dbv + dgv + 1.0f);
            size_t off = (size_t)row * DD + cg * 8;
            float4 y0 = *reinterpret_cast<const float4*>(Y + off);
            float4 y1 = *reinterpret_cast<const float4*>(Y + off + 4);
            float4 x0 = *reinterpret_cast<const float4*>(X + off);
            float4 x1 = *reinterpret_cast<const float4*>(X + off + 4);
            float4 g0 = *reinterpret_cast<const float4*>(Ag + off);
            float4 g1 = *reinterpret_cast<const float4*>(Ag + off + 4);
            float yv[8] = {y0.x, y0.y, y0.z, y0.w, y1.x, y1.y, y1.z, y1.w};
            float xv[8] = {x0.x, x0.y, x0.z, x0.w, x1.x, x1.y, x1.z, x1.w};
            float gv[8] = {g0.x, g0.y, g0.z, g0.w, g1.x, g1.y, g1.z, g1.w};
            float ov[8];
#pragma unroll
            for (int j = 0; j < 8; ++j) {
                float yhat = aS[i][j] - dbv * aP1[i][j] - dgv * aP2[i][j]
                             + xv[j] + dgv * yv[j] - gv[j];
                ov[j] = (1.0f - AL) * yv[j] + yhat * aq;
            }
            *reinterpret_cast<float4*>(Yn + off) = make_float4(ov[0], ov[1], ov[2], ov[3]);
            *reinterpret_cast<float4*>(Yn + off + 4) = make_float4(ov[4], ov[5], ov[6], ov[7]);
        }
    }
}

// ---------------- host ----------------

extern "C" void kernel_launch(void* const* d_in, const int* in_sizes, int n_in,
                              void* d_out, int out_size, void* d_ws, size_t ws_size,
                              hipStream_t stream) {
    const float* X   = (const float*)d_in[0];
    const float* H1  = (const float*)d_in[1];
    const float* H2  = (const float*)d_in[2];
    const float* wb  = (const float*)d_in[3];
    const float* wg  = (const float*)d_in[4];
    const float* db  = (const float*)d_in[5];
    const float* dg  = (const float*)d_in[6];
    const int* srcb  = (const int*)d_in[7];
    const int* dstb  = (const int*)d_in[8];
    const int* srcg  = (const int*)d_in[9];
    const int* dstg  = (const int*)d_in[10];
    const int N = in_sizes[5];
    const int E = in_sizes[3];
    float* Yout = (float*)d_out;

    char* p = (char*)d_ws;
    auto alloc = [&](size_t b) -> void* {
        void* r = (void*)p;
        p += (b + 255) & ~(size_t)255;
        return r;
    };
    float* P1 = (float*)alloc((size_t)DD * DD * 4);
    float* S1 = (float*)alloc((size_t)DD * DD * 4);
    float* P2 = (float*)alloc((size_t)DD * DD * 4);
    float* S2 = (float*)alloc((size_t)DD * DD * 4);
    int* degb = (int*)alloc((size_t)N * 4);
    int* degg = (int*)alloc((size_t)N * 4);
    int* rpb  = (int*)alloc((size_t)(N + 1) * 4);
    int* rpg  = (int*)alloc((size_t)(N + 1) * 4);
    int* curb = (int*)alloc((size_t)N * 4);
    int* curg = (int*)alloc((size_t)N * 4);
    int2* eb  = (int2*)alloc((size_t)E * 8);
    int2* eg  = (int2*)alloc((size_t)E * 8);
    float* AbY = (float*)alloc((size_t)N * DD * 4);
    float* AgY = (float*)alloc((size_t)N * DD * 4);
    float* Yw  = (float*)alloc((size_t)N * DD * 4);

    hipMemsetAsync(degb, 0, (size_t)N * 4, stream);
    hipMemsetAsync(degg, 0, (size_t)N * 4, stream);

    int gE = (E + 255) / 256;
    count2_k<<<2 * gE, 256, 0, stream>>>(dstb, dstg, degb, degg, E, gE);
    scan2_k<<<2, 1024, 0, stream>>>(degb, degg, rpb, rpg, curb, curg, N);
    fill2_k<<<2 * gE, 256, 0, stream>>>(srcb, dstb, wb, srcg, dstg, wg,
                                        curb, curg, eb, eg, E, gE);
    prep_k<<<64, 256, 0, stream>>>(H1, P1, S1);
    prep_k<<<64, 256, 0, stream>>>(H2, P2, S2);

    const float* Ycur = X;
    float* Ybufs[2] = {Yw, Yout};
    int gs = (N + 3) / 4;
    int gd = (N + 63) / 64;
    for (int s = 0; s < 8; ++s) {
        spmm_k<<<gs, 256, 0, stream>>>(rpb, eb, Ycur, AbY, N);
        spmm_k<<<gs, 256, 0, stream>>>(rpg, eg, Ycur, AgY, N);
        float* Yn = Ybufs[s & 1];
        dense_k<<<gd, 128, 0, stream>>>(Ycur, X, AbY, AgY, db, dg,
                                        P1, P2, S1, S2, Yn, N);
        Ycur = Yn;
    }
}